// Round 1
// baseline (449.352 us; speedup 1.0000x reference)
//
#include <hip/hip_runtime.h>
#include <math.h>

// ---- problem constants (fixed by setup_inputs) ----
constexpr int B  = 8, L = 2048;
constexpr int IN68 = 68;           // enc_in + mark
constexpr int DI = 512;            // d_inner
constexpr int DS = 16;             // d_state
constexpr int PL = 96, CO = 64;    // pred_len, c_out
constexpr int NC = 16, CLEN = 128; // scan chunks
constexpr int TSTART = L - PL;     // 1952
constexpr int C0 = TSTART / CLEN;  // 15 (chunk containing TSTART)
constexpr int T0 = C0 * CLEN;      // 1920

// ---- workspace layout (float offsets) ----
constexpr size_t o_xp   = 0;                          // B*L*DI   (reused as dt after conv)
constexpr size_t o_xc   = o_xp  + (size_t)B*L*DI;     // B*L*DI
constexpr size_t o_z    = o_xc  + (size_t)B*L*DI;     // B*PL*DI
constexpr size_t o_Bm   = o_z   + (size_t)B*PL*DI;    // B*L*DS
constexpr size_t o_Cm   = o_Bm  + (size_t)B*L*DS;     // B*L*DS
constexpr size_t o_WfT  = o_Cm  + (size_t)B*L*DS;     // 69*1024 (row 68 = fused bias)
constexpr size_t o_WxT  = o_WfT + 69*1024;            // 512*48
constexpr size_t o_WdtT = o_WxT + 512*48;             // 16*512
constexpr size_t o_Wcb  = o_WdtT+ 16*512;             // 512*64
constexpr size_t o_P    = o_Wcb + 512*64;             // NC*B*DI*DS
constexpr size_t o_Bc   = o_P   + (size_t)NC*B*DI*DS; // NC*B*DI*DS
constexpr size_t o_Hin  = o_Bc  + (size_t)NC*B*DI*DS; // B*DI*DS
constexpr size_t o_yf   = o_Hin + (size_t)B*DI*DS;    // B*PL*DI

// ---------- K0: weight fusion / transposes ----------
__global__ __launch_bounds__(256) void k_prep(
        const float* __restrict__ W_it, const float* __restrict__ b_it,
        const float* __restrict__ W_in, const float* __restrict__ W_out,
        const float* __restrict__ W_fc, const float* __restrict__ W_x,
        const float* __restrict__ W_dt, float* __restrict__ ws)
{
    int idx = blockIdx.x * 256 + threadIdx.x;
    float* WfT  = ws + o_WfT;
    float* WxT  = ws + o_WxT;
    float* WdtT = ws + o_WdtT;
    float* Wcb  = ws + o_Wcb;
    if (idx < 69*1024) {
        int k = idx / 1024, j = idx % 1024;
        float acc = 0.f;
        if (k < 68) { for (int m = 0; m < 256; ++m) acc += W_in[j*256+m] * W_it[m*68+k]; }
        else        { for (int m = 0; m < 256; ++m) acc += W_in[j*256+m] * b_it[m]; }
        WfT[idx] = acc;
        return;
    }
    idx -= 69*1024;
    if (idx < 512*48) { int k = idx/48, r = idx%48; WxT[idx] = W_x[r*512+k]; return; }
    idx -= 512*48;
    if (idx < 16*512) { int r = idx>>9, j = idx&511; WdtT[idx] = W_dt[j*16+r]; return; }
    idx -= 16*512;
    if (idx < 512*64) {
        int d = idx>>6, c = idx&63;
        float acc = 0.f;
        for (int m = 0; m < 256; ++m) acc += W_fc[c*256+m] * W_out[m*512+d];
        Wcb[idx] = acc;
    }
}

// ---------- K1: fused input+in projection: xp (all t), z (last 96 t only) ----------
__global__ __launch_bounds__(256) void k_xz(const float* __restrict__ x_enc,
        const float* __restrict__ x_mark, float* __restrict__ ws)
{
    __shared__ float sin68[16][IN68];
    const float* WfT = ws + o_WfT;
    float* xp = ws + o_xp;
    float* z  = ws + o_z;
    int tid = threadIdx.x;
    int bt0 = blockIdx.x * 16;
    int tl0 = bt0 & (L-1);
    bool needZ = (tl0 >= TSTART);   // tiles are aligned: fully in or out
    for (int i = tid; i < 16*IN68; i += 256) {
        int tt = i / IN68, k = i % IN68;
        int bt = bt0 + tt;
        sin68[tt][k] = (k < 64) ? x_enc[bt*64 + k] : x_mark[bt*4 + (k-64)];
    }
    __syncthreads();
    float a0[16], a1[16], a2[16], a3[16];
    #pragma unroll
    for (int tt = 0; tt < 16; ++tt) { a0[tt]=0.f; a1[tt]=0.f; a2[tt]=0.f; a3[tt]=0.f; }
    if (needZ) {
        for (int k = 0; k < IN68; ++k) {
            float w0 = WfT[k*1024 + tid];
            float w1 = WfT[k*1024 + 256 + tid];
            float w2 = WfT[k*1024 + 512 + tid];
            float w3 = WfT[k*1024 + 768 + tid];
            #pragma unroll
            for (int tt = 0; tt < 16; ++tt) {
                float v = sin68[tt][k];
                a0[tt] += v*w0; a1[tt] += v*w1; a2[tt] += v*w2; a3[tt] += v*w3;
            }
        }
        float b0 = WfT[68*1024 + tid],       b1 = WfT[68*1024 + 256 + tid];
        float b2 = WfT[68*1024 + 512 + tid], b3 = WfT[68*1024 + 768 + tid];
        int b = bt0 >> 11;
        #pragma unroll
        for (int tt = 0; tt < 16; ++tt) {
            int bt = bt0 + tt;
            xp[(size_t)bt*DI + tid]       = a0[tt] + b0;
            xp[(size_t)bt*DI + 256 + tid] = a1[tt] + b1;
            int row = b*PL + (tl0 + tt - TSTART);
            z[(size_t)row*DI + tid]       = a2[tt] + b2;
            z[(size_t)row*DI + 256 + tid] = a3[tt] + b3;
        }
    } else {
        for (int k = 0; k < IN68; ++k) {
            float w0 = WfT[k*1024 + tid];
            float w1 = WfT[k*1024 + 256 + tid];
            #pragma unroll
            for (int tt = 0; tt < 16; ++tt) {
                float v = sin68[tt][k];
                a0[tt] += v*w0; a1[tt] += v*w1;
            }
        }
        float b0 = WfT[68*1024 + tid], b1 = WfT[68*1024 + 256 + tid];
        #pragma unroll
        for (int tt = 0; tt < 16; ++tt) {
            int bt = bt0 + tt;
            xp[(size_t)bt*DI + tid]       = a0[tt] + b0;
            xp[(size_t)bt*DI + 256 + tid] = a1[tt] + b1;
        }
    }
}

// ---------- K2: causal depthwise conv(4) + SiLU ----------
__global__ __launch_bounds__(256) void k_conv(const float* __restrict__ conv_w,
        const float* __restrict__ conv_b, float* __restrict__ ws)
{
    const float* xp = ws + o_xp;
    float* xc = ws + o_xc;
    int idx = blockIdx.x*256 + threadIdx.x;   // B*L*DI
    int d = idx & (DI-1);
    int bt = idx >> 9;
    int t = bt & (L-1);
    float acc = conv_b[d];
    #pragma unroll
    for (int i = 0; i < 4; ++i) {
        int tt = t - 3 + i;
        if (tt >= 0) acc += xp[(size_t)(bt-3+i)*DI + d] * conv_w[d*4+i];
    }
    float s = 1.f/(1.f + __expf(-acc));
    xc[idx] = acc * s;
}

// ---------- K3: x_db (B,C) + dt = softplus(.@W_dt.T + b_dt) ----------
__global__ __launch_bounds__(384) void k_xdb(const float* __restrict__ b_dt,
        float* __restrict__ ws)
{
    __shared__ float xcs[8][DI];
    __shared__ float s[8][48];
    const float* xc  = ws + o_xc;
    const float* WxT = ws + o_WxT;
    const float* WdtT= ws + o_WdtT;
    float* dt = ws + o_xp;   // reuse xp buffer (conv already consumed it)
    float* Bm = ws + o_Bm;
    float* Cm = ws + o_Cm;
    int tid = threadIdx.x;
    int bt0 = blockIdx.x * 8;
    for (int i = tid; i < 8*DI; i += 384)
        xcs[i>>9][i&511] = xc[(size_t)(bt0 + (i>>9))*DI + (i&511)];
    __syncthreads();
    {
        int tt = tid / 48, r = tid % 48;      // 384 == 8*48 exactly
        float acc = 0.f;
        for (int k = 0; k < DI; ++k)
            acc += xcs[tt][k] * WxT[k*48 + r];
        s[tt][r] = acc;
        int bt = bt0 + tt;
        if (r >= 16 && r < 32) Bm[bt*DS + (r-16)] = acc;
        else if (r >= 32)      Cm[bt*DS + (r-32)] = acc;
    }
    __syncthreads();
    for (int i = tid; i < 8*DI; i += 384) {
        int tt = i >> 9, j = i & 511;
        float acc = b_dt[j];
        #pragma unroll
        for (int r = 0; r < 16; ++r) acc += s[tt][r] * WdtT[r*512 + j];
        float sp = fmaxf(acc, 0.f) + log1pf(expf(-fabsf(acc)));   // stable softplus
        dt[(size_t)(bt0+tt)*DI + j] = sp;
    }
}

// ---------- K4: chunked scan phase 1: per-chunk (prod a, local h) ----------
__global__ __launch_bounds__(256) void k_scan1(const float* __restrict__ A_log,
        float* __restrict__ ws)
{
    const float* dt = ws + o_xp;
    const float* xc = ws + o_xc;
    const float* Bm = ws + o_Bm;
    float* P  = ws + o_P;
    float* Bc = ws + o_Bc;
    int tid = threadIdx.x;
    int n = tid & 15, dl = tid >> 4;
    int bx = blockIdx.x;                 // B*32*NC = 4096
    int c = bx & (NC-1);
    int dtile = (bx >> 4) & 31;
    int b = bx >> 9;
    int d = dtile*16 + dl;
    float aco = -__expf(A_log[d*DS + n]);
    float h = 0.f, p = 1.f;
    int btBase = b*L + c*CLEN;
    const float* dtp = dt + (size_t)btBase*DI + d;
    const float* xcp = xc + (size_t)btBase*DI + d;
    const float* bmp = Bm + (size_t)btBase*DS + n;
    for (int t = 0; t < CLEN; ++t) {
        float dtv = dtp[(size_t)t*DI];
        float xcv = xcp[(size_t)t*DI];
        float bv  = bmp[(size_t)t*DS];
        float a = __expf(dtv * aco);
        h = fmaf(a, h, dtv * bv * xcv);
        p *= a;
    }
    size_t idx4 = ((size_t)(b*DI + d))*DS + n;
    P [(size_t)c*(B*DI*DS) + idx4] = p;
    Bc[(size_t)c*(B*DI*DS) + idx4] = h;
}

// ---------- K5: combine chunk states -> state entering chunk C0 ----------
__global__ __launch_bounds__(256) void k_comb(float* __restrict__ ws)
{
    const float* P  = ws + o_P;
    const float* Bc = ws + o_Bc;
    float* Hin = ws + o_Hin;
    int idx = blockIdx.x*256 + threadIdx.x;  // B*DI*DS = 65536
    float h = 0.f;
    for (int k = 0; k < C0; ++k)
        h = P[(size_t)k*(B*DI*DS) + idx]*h + Bc[(size_t)k*(B*DI*DS) + idx];
    Hin[idx] = h;
}

// ---------- K6: replay last chunk, emit gated y for t in [TSTART, L) ----------
__global__ __launch_bounds__(256) void k_scan2(const float* __restrict__ A_log,
        const float* __restrict__ Dp, float* __restrict__ ws)
{
    const float* dt = ws + o_xp;
    const float* xc = ws + o_xc;
    const float* Bm = ws + o_Bm;
    const float* Cm = ws + o_Cm;
    const float* z  = ws + o_z;
    const float* Hin= ws + o_Hin;
    float* yf = ws + o_yf;
    int tid = threadIdx.x;
    int n = tid & 15, dl = tid >> 4;
    int bx = blockIdx.x;                 // B*32 = 256
    int dtile = bx & 31, b = bx >> 5;
    int d = dtile*16 + dl;
    float aco = -__expf(A_log[d*DS + n]);
    float Dv = Dp[d];
    float h = Hin[((size_t)(b*DI + d))*DS + n];
    for (int t = T0; t < L; ++t) {
        int bt = b*L + t;
        float dtv = dt[(size_t)bt*DI + d];
        float xcv = xc[(size_t)bt*DI + d];
        float bv  = Bm[(size_t)bt*DS + n];
        float a = __expf(dtv * aco);
        h = fmaf(a, h, dtv * bv * xcv);
        if (t >= TSTART) {
            float y = h * Cm[(size_t)bt*DS + n];
            y += __shfl_xor(y, 1, 16);
            y += __shfl_xor(y, 2, 16);
            y += __shfl_xor(y, 4, 16);
            y += __shfl_xor(y, 8, 16);
            if (n == 0) {
                int row = b*PL + (t - TSTART);
                float zv = z[(size_t)row*DI + d];
                float sig = 1.f/(1.f + __expf(-zv));
                yf[(size_t)row*DI + d] = (y + xcv*Dv) * (zv * sig);
            }
        }
    }
}

// ---------- K7: out = yf @ W_comb.T + b_fc ----------
__global__ __launch_bounds__(64) void k_final(const float* __restrict__ b_fc,
        float* __restrict__ out, const float* __restrict__ ws_c)
{
    __shared__ float ys[DI];
    const float* yf  = ws_c + o_yf;
    const float* Wcb = ws_c + o_Wcb;
    int row = blockIdx.x;     // B*PL = 768
    int c = threadIdx.x;      // 64
    for (int i = c; i < DI; i += 64) ys[i] = yf[(size_t)row*DI + i];
    __syncthreads();
    float acc = b_fc[c];
    for (int d = 0; d < DI; ++d) acc += ys[d] * Wcb[d*64 + c];
    out[row*CO + c] = acc;
}

extern "C" void kernel_launch(void* const* d_in, const int* in_sizes, int n_in,
                              void* d_out, int out_size, void* d_ws, size_t ws_size,
                              hipStream_t stream)
{
    const float* x_enc  = (const float*)d_in[0];
    const float* x_mark = (const float*)d_in[1];
    const float* W_it   = (const float*)d_in[4];
    const float* b_it   = (const float*)d_in[5];
    const float* W_in   = (const float*)d_in[6];
    const float* conv_w = (const float*)d_in[7];
    const float* conv_b = (const float*)d_in[8];
    const float* W_x    = (const float*)d_in[9];
    const float* W_dt   = (const float*)d_in[10];
    const float* b_dt   = (const float*)d_in[11];
    const float* A_log  = (const float*)d_in[12];
    const float* Dp     = (const float*)d_in[13];
    const float* W_out  = (const float*)d_in[14];
    const float* W_fc   = (const float*)d_in[15];
    const float* b_fc   = (const float*)d_in[16];
    float* ws  = (float*)d_ws;
    float* out = (float*)d_out;

    constexpr int prep_total = 69*1024 + 512*48 + 16*512 + 512*64;
    k_prep <<<(prep_total + 255)/256, 256, 0, stream>>>(W_it, b_it, W_in, W_out, W_fc, W_x, W_dt, ws);
    k_xz   <<<B*L/16,      256, 0, stream>>>(x_enc, x_mark, ws);
    k_conv <<<B*L*DI/256,  256, 0, stream>>>(conv_w, conv_b, ws);
    k_xdb  <<<B*L/8,       384, 0, stream>>>(b_dt, ws);
    k_scan1<<<B*32*NC,     256, 0, stream>>>(A_log, ws);
    k_comb <<<B*DI*DS/256, 256, 0, stream>>>(ws);
    k_scan2<<<B*32,        256, 0, stream>>>(A_log, Dp, ws);
    k_final<<<B*PL,        64,  0, stream>>>(b_fc, out, ws);
}

// Round 2
// 327.695 us; speedup vs baseline: 1.3713x; 1.3713x over previous
//
#include <hip/hip_runtime.h>
#include <math.h>

// ---- problem constants (fixed by setup_inputs) ----
constexpr int B  = 8, L = 2048;
constexpr int IN68 = 68;           // enc_in + mark
constexpr int DI = 512;            // d_inner
constexpr int DS = 16;             // d_state
constexpr int PL = 96, CO = 64;    // pred_len, c_out
constexpr int NC = 16, CLEN = 128; // scan chunks
constexpr int TSTART = L - PL;     // 1952
constexpr int C0 = TSTART / CLEN;  // 15 (chunk containing TSTART)
constexpr int T0 = C0 * CLEN;      // 1920

// ---- workspace layout (float offsets) ----
constexpr size_t o_dt   = 0;                          // B*L*DI (dt after k_xdb)
constexpr size_t o_xc   = o_dt  + (size_t)B*L*DI;     // B*L*DI
constexpr size_t o_z    = o_xc  + (size_t)B*L*DI;     // B*PL*DI  (holds silu(z))
constexpr size_t o_Bm   = o_z   + (size_t)B*PL*DI;    // B*L*DS
constexpr size_t o_Cm   = o_Bm  + (size_t)B*L*DS;     // B*L*DS
constexpr size_t o_WfT  = o_Cm  + (size_t)B*L*DS;     // 69*1024 (row 68 = fused bias)
constexpr size_t o_WxT  = o_WfT + 69*1024;            // 512*48
constexpr size_t o_WdtT = o_WxT + 512*48;             // 16*512
constexpr size_t o_Wcb  = o_WdtT+ 16*512;             // 512*64
constexpr size_t o_P    = o_Wcb + 512*64;             // NC*B*DI*DS
constexpr size_t o_Bc   = o_P   + (size_t)NC*B*DI*DS; // NC*B*DI*DS
constexpr size_t o_yf   = o_Bc  + (size_t)NC*B*DI*DS; // B*PL*DI

// ---------- K0: weight fusion / transposes ----------
__global__ __launch_bounds__(256) void k_prep(
        const float* __restrict__ W_it, const float* __restrict__ b_it,
        const float* __restrict__ W_in, const float* __restrict__ W_out,
        const float* __restrict__ W_fc, const float* __restrict__ W_x,
        const float* __restrict__ W_dt, float* __restrict__ ws)
{
    int idx = blockIdx.x * 256 + threadIdx.x;
    float* WfT  = ws + o_WfT;
    float* WxT  = ws + o_WxT;
    float* WdtT = ws + o_WdtT;
    float* Wcb  = ws + o_Wcb;
    if (idx < 69*1024) {
        int k = idx / 1024, j = idx % 1024;
        float acc = 0.f;
        if (k < 68) { for (int m = 0; m < 256; ++m) acc += W_in[j*256+m] * W_it[m*68+k]; }
        else        { for (int m = 0; m < 256; ++m) acc += W_in[j*256+m] * b_it[m]; }
        WfT[idx] = acc;
        return;
    }
    idx -= 69*1024;
    if (idx < 512*48) { int k = idx/48, r = idx%48; WxT[idx] = W_x[r*512+k]; return; }
    idx -= 512*48;
    if (idx < 16*512) { int r = idx>>9, j = idx&511; WdtT[idx] = W_dt[j*16+r]; return; }
    idx -= 16*512;
    if (idx < 512*64) {
        int d = idx>>6, c = idx&63;
        float acc = 0.f;
        for (int m = 0; m < 256; ++m) acc += W_fc[c*256+m] * W_out[m*512+d];
        Wcb[idx] = acc;
    }
}

// ---------- K1: fused input-proj + causal conv(4) + SiLU -> xc; plus silu(z) ----------
// blocks [0,1024): xc for a 16-t tile (xp computed into LDS with 3-row halo).
// blocks [1024,1072): silu(z) for the last 96 t of each batch.
__global__ __launch_bounds__(256) void k_xzc(const float* __restrict__ x_enc,
        const float* __restrict__ x_mark, const float* __restrict__ conv_w,
        const float* __restrict__ conv_b, float* __restrict__ ws)
{
    __shared__ float s68[19][IN68];
    __shared__ float xps[19][DI];
    const float* WfT = ws + o_WfT;
    int tid = threadIdx.x;
    if (blockIdx.x < 1024) {
        int bt0 = blockIdx.x * 16;
        int b = bt0 >> 11, tl0 = bt0 & (L-1);
        for (int i = tid; i < 19*IN68; i += 256) {
            int row = i / IN68, k = i % IN68;
            int t = tl0 - 3 + row;
            float v = 0.f;
            if (t >= 0) v = (k < 64) ? x_enc[(b*L + t)*64 + k] : x_mark[(b*L + t)*4 + (k-64)];
            s68[row][k] = v;
        }
        __syncthreads();
        float a0[19], a1[19];
        #pragma unroll
        for (int r = 0; r < 19; ++r) { a0[r] = 0.f; a1[r] = 0.f; }
        for (int k = 0; k < IN68; ++k) {
            float w0 = WfT[k*1024 + tid];
            float w1 = WfT[k*1024 + 256 + tid];
            #pragma unroll
            for (int r = 0; r < 19; ++r) {
                float v = s68[r][k];
                a0[r] += v*w0; a1[r] += v*w1;
            }
        }
        float b0 = WfT[68*1024 + tid], b1 = WfT[68*1024 + 256 + tid];
        #pragma unroll
        for (int r = 0; r < 19; ++r) {
            bool valid = (tl0 - 3 + r) >= 0;
            xps[r][tid]       = valid ? a0[r] + b0 : 0.f;
            xps[r][tid + 256] = valid ? a1[r] + b1 : 0.f;
        }
        __syncthreads();
        float cw0[4], cw1[4];
        #pragma unroll
        for (int i = 0; i < 4; ++i) { cw0[i] = conv_w[tid*4+i]; cw1[i] = conv_w[(tid+256)*4+i]; }
        float cb0 = conv_b[tid], cb1 = conv_b[tid+256];
        float* xc = ws + o_xc;
        #pragma unroll
        for (int tt = 0; tt < 16; ++tt) {
            float acc0 = cb0, acc1 = cb1;
            #pragma unroll
            for (int i = 0; i < 4; ++i) {
                acc0 += xps[tt+i][tid]     * cw0[i];
                acc1 += xps[tt+i][tid+256] * cw1[i];
            }
            float v0 = acc0 / (1.f + __expf(-acc0));
            float v1 = acc1 / (1.f + __expf(-acc1));
            size_t bt = bt0 + tt;
            xc[bt*DI + tid]       = v0;
            xc[bt*DI + 256 + tid] = v1;
        }
    } else {
        // silu(z) for rows t in [TSTART, L)
        int zb = blockIdx.x - 1024;        // 0..47
        int b = zb / 6;
        int tl0 = TSTART + (zb % 6) * 16;
        for (int i = tid; i < 16*IN68; i += 256) {
            int row = i / IN68, k = i % IN68;
            int t = tl0 + row;
            s68[row][k] = (k < 64) ? x_enc[(b*L + t)*64 + k] : x_mark[(b*L + t)*4 + (k-64)];
        }
        __syncthreads();
        float a2[16], a3[16];
        #pragma unroll
        for (int r = 0; r < 16; ++r) { a2[r] = 0.f; a3[r] = 0.f; }
        for (int k = 0; k < IN68; ++k) {
            float w2 = WfT[k*1024 + 512 + tid];
            float w3 = WfT[k*1024 + 768 + tid];
            #pragma unroll
            for (int r = 0; r < 16; ++r) {
                float v = s68[r][k];
                a2[r] += v*w2; a3[r] += v*w3;
            }
        }
        float b2 = WfT[68*1024 + 512 + tid], b3 = WfT[68*1024 + 768 + tid];
        float* z = ws + o_z;
        #pragma unroll
        for (int r = 0; r < 16; ++r) {
            float z0 = a2[r] + b2, z1 = a3[r] + b3;
            size_t row = b*PL + (tl0 + r - TSTART);
            z[row*DI + tid]       = z0 / (1.f + __expf(-z0));
            z[row*DI + 256 + tid] = z1 / (1.f + __expf(-z1));
        }
    }
}

// ---------- K2: x_db (B,C) + dt = softplus(.@W_dt.T + b_dt) ----------
__global__ __launch_bounds__(384) void k_xdb(const float* __restrict__ b_dt,
        float* __restrict__ ws)
{
    __shared__ float xcs[8][DI];
    __shared__ float s[8][48];
    const float* xc  = ws + o_xc;
    const float* WxT = ws + o_WxT;
    const float* WdtT= ws + o_WdtT;
    float* dt = ws + o_dt;
    float* Bm = ws + o_Bm;
    float* Cm = ws + o_Cm;
    int tid = threadIdx.x;
    int bt0 = blockIdx.x * 8;
    for (int i = tid; i < 8*DI; i += 384)
        xcs[i>>9][i&511] = xc[(size_t)(bt0 + (i>>9))*DI + (i&511)];
    __syncthreads();
    {
        int tt = tid / 48, r = tid % 48;      // 384 == 8*48 exactly
        float acc0 = 0.f, acc1 = 0.f, acc2 = 0.f, acc3 = 0.f;
        for (int k = 0; k < DI; k += 4) {
            acc0 += xcs[tt][k]   * WxT[k*48 + r];
            acc1 += xcs[tt][k+1] * WxT[(k+1)*48 + r];
            acc2 += xcs[tt][k+2] * WxT[(k+2)*48 + r];
            acc3 += xcs[tt][k+3] * WxT[(k+3)*48 + r];
        }
        float acc = (acc0+acc1) + (acc2+acc3);
        s[tt][r] = acc;
        int bt = bt0 + tt;
        if (r >= 16 && r < 32) Bm[bt*DS + (r-16)] = acc;
        else if (r >= 32)      Cm[bt*DS + (r-32)] = acc;
    }
    __syncthreads();
    for (int i = tid; i < 8*DI; i += 384) {
        int tt = i >> 9, j = i & 511;
        float acc = b_dt[j];
        #pragma unroll
        for (int r = 0; r < 16; ++r) acc += s[tt][r] * WdtT[r*512 + j];
        float sp = fmaxf(acc, 0.f) + log1pf(expf(-fabsf(acc)));   // stable softplus
        dt[(size_t)(bt0+tt)*DI + j] = sp;
    }
}

// ---------- K3: chunked scan phase 1 (chunks 0..14): per-chunk (prod a, local h) ----------
// thread-per-d: h[16], aco[16] in registers; dt/xc loads coalesced; Bm staged in LDS.
__global__ __launch_bounds__(256) void k_scan1(const float* __restrict__ A_log,
        float* __restrict__ ws)
{
    __shared__ float bs[CLEN*DS];   // 8 KB
    const float* dt = ws + o_dt;
    const float* xc = ws + o_xc;
    const float* Bm = ws + o_Bm;
    float* P  = ws + o_P;
    float* Bc = ws + o_Bc;
    int tid = threadIdx.x;
    int bx = blockIdx.x;            // 240 = B * 15 * 2
    int b = bx / 30;
    int r = bx % 30;
    int c = r % 15;
    int half = r / 15;
    int d = half*256 + tid;
    float aco[16], h[16];
    #pragma unroll
    for (int n = 0; n < 16; ++n) {
        aco[n] = -__expf(A_log[d*DS + n]);
        h[n] = 0.f;
    }
    size_t btBase = (size_t)b*L + c*CLEN;
    for (int i = tid; i < CLEN*DS; i += 256) bs[i] = Bm[btBase*DS + i];
    __syncthreads();
    const float* dtp = dt + btBase*DI + d;
    const float* xcp = xc + btBase*DI + d;
    float sdt = 0.f;
    float dtv = dtp[0], xcv = xcp[0];
    for (int t = 0; t < CLEN; ++t) {
        float dtn = 0.f, xcn = 0.f;
        if (t < CLEN-1) { dtn = dtp[(size_t)(t+1)*DI]; xcn = xcp[(size_t)(t+1)*DI]; }
        float dtx = dtv * xcv;
        sdt += dtv;
        #pragma unroll
        for (int n = 0; n < 16; ++n) {
            float a = __expf(aco[n] * dtv);
            h[n] = fmaf(a, h[n], bs[t*DS + n] * dtx);
        }
        dtv = dtn; xcv = xcn;
    }
    size_t base = (((size_t)c*B + b)*DI + d)*DS;
    #pragma unroll
    for (int n = 0; n < 16; ++n) {
        P [base + n] = __expf(aco[n] * sdt);
        Bc[base + n] = h[n];
    }
}

// ---------- K4: combine chunks 0..14 + replay last chunk from LDS + gate ----------
// thread-per-(d,n): 512 threads = 32 d x 16 n; all replay data staged in LDS.
__global__ __launch_bounds__(512) void k_scan2(const float* __restrict__ A_log,
        const float* __restrict__ Dp, float* __restrict__ ws)
{
    __shared__ float dts[CLEN*32];  // 16 KB
    __shared__ float xds[CLEN*32];  // 16 KB
    __shared__ float bss[CLEN*DS];  // 8 KB
    __shared__ float css[CLEN*DS];  // 8 KB
    __shared__ float szs[PL*32];    // 12 KB
    const float* dt = ws + o_dt;
    const float* xc = ws + o_xc;
    const float* Bm = ws + o_Bm;
    const float* Cm = ws + o_Cm;
    const float* z  = ws + o_z;
    const float* P  = ws + o_P;
    const float* Bc = ws + o_Bc;
    float* yf = ws + o_yf;
    int tid = threadIdx.x;
    int bx = blockIdx.x;           // 128 = B * 16
    int b = bx >> 4, dtile = bx & 15;
    int n = tid & 15, dl = tid >> 4;   // dl in [0,32)
    int d = dtile*32 + dl;
    size_t btBase = (size_t)b*L + T0;
    // stage
    for (int i = tid; i < CLEN*32; i += 512) {
        int tt = i >> 5, j = i & 31;
        size_t g = (btBase + tt)*DI + dtile*32 + j;
        dts[i] = dt[g];
        xds[i] = xc[g];
    }
    for (int i = tid; i < CLEN*DS; i += 512) {
        bss[i] = Bm[btBase*DS + i];
        css[i] = Cm[btBase*DS + i];
    }
    for (int i = tid; i < PL*32; i += 512) {
        int tt = i >> 5, j = i & 31;
        szs[i] = z[((size_t)b*PL + tt)*DI + dtile*32 + j];
    }
    // combine chunk states -> h entering chunk C0
    float aco = -__expf(A_log[d*DS + n]);
    float Dv = Dp[d];
    float h = 0.f;
    for (int c = 0; c < C0; ++c) {
        size_t idx = (((size_t)c*B + b)*DI + d)*DS + n;
        h = P[idx]*h + Bc[idx];
    }
    __syncthreads();
    // replay
    for (int t = 0; t < CLEN; ++t) {
        float dtv = dts[t*32 + dl];
        float xcv = xds[t*32 + dl];
        float bv  = bss[t*DS + n];
        float a = __expf(aco * dtv);
        h = fmaf(a, h, dtv * bv * xcv);
        if (t >= TSTART - T0) {
            float y = h * css[t*DS + n];
            y += __shfl_xor(y, 1, 16);
            y += __shfl_xor(y, 2, 16);
            y += __shfl_xor(y, 4, 16);
            y += __shfl_xor(y, 8, 16);
            if (n == 0) {
                int row = t - (TSTART - T0);
                yf[((size_t)b*PL + row)*DI + d] = (y + xcv*Dv) * szs[row*32 + dl];
            }
        }
    }
}

// ---------- K5: out = yf @ W_comb.T + b_fc ----------
__global__ __launch_bounds__(64) void k_final(const float* __restrict__ b_fc,
        float* __restrict__ out, const float* __restrict__ ws_c)
{
    __shared__ float ys[DI];
    const float* yf  = ws_c + o_yf;
    const float* Wcb = ws_c + o_Wcb;
    int row = blockIdx.x;     // B*PL = 768
    int c = threadIdx.x;      // 64
    for (int i = c; i < DI; i += 64) ys[i] = yf[(size_t)row*DI + i];
    __syncthreads();
    float a0 = b_fc[c], a1 = 0.f, a2 = 0.f, a3 = 0.f;
    for (int d = 0; d < DI; d += 4) {
        a0 += ys[d]   * Wcb[d*64 + c];
        a1 += ys[d+1] * Wcb[(d+1)*64 + c];
        a2 += ys[d+2] * Wcb[(d+2)*64 + c];
        a3 += ys[d+3] * Wcb[(d+3)*64 + c];
    }
    out[row*CO + c] = (a0+a1) + (a2+a3);
}

extern "C" void kernel_launch(void* const* d_in, const int* in_sizes, int n_in,
                              void* d_out, int out_size, void* d_ws, size_t ws_size,
                              hipStream_t stream)
{
    const float* x_enc  = (const float*)d_in[0];
    const float* x_mark = (const float*)d_in[1];
    const float* W_it   = (const float*)d_in[4];
    const float* b_it   = (const float*)d_in[5];
    const float* W_in   = (const float*)d_in[6];
    const float* conv_w = (const float*)d_in[7];
    const float* conv_b = (const float*)d_in[8];
    const float* W_x    = (const float*)d_in[9];
    const float* W_dt   = (const float*)d_in[10];
    const float* b_dt   = (const float*)d_in[11];
    const float* A_log  = (const float*)d_in[12];
    const float* Dp     = (const float*)d_in[13];
    const float* W_out  = (const float*)d_in[14];
    const float* W_fc   = (const float*)d_in[15];
    const float* b_fc   = (const float*)d_in[16];
    float* ws  = (float*)d_ws;
    float* out = (float*)d_out;

    constexpr int prep_total = 69*1024 + 512*48 + 16*512 + 512*64;
    k_prep <<<(prep_total + 255)/256, 256, 0, stream>>>(W_it, b_it, W_in, W_out, W_fc, W_x, W_dt, ws);
    k_xzc  <<<1072,     256, 0, stream>>>(x_enc, x_mark, conv_w, conv_b, ws);
    k_xdb  <<<B*L/8,    384, 0, stream>>>(b_dt, ws);
    k_scan1<<<B*15*2,   256, 0, stream>>>(A_log, ws);
    k_scan2<<<B*16,     512, 0, stream>>>(A_log, Dp, ws);
    k_final<<<B*PL,     64,  0, stream>>>(b_fc, out, ws);
}

// Round 3
// 301.505 us; speedup vs baseline: 1.4904x; 1.0869x over previous
//
#include <hip/hip_runtime.h>
#include <math.h>

// ---- problem constants (fixed by setup_inputs) ----
constexpr int B  = 8, L = 2048;
constexpr int IN68 = 68;           // enc_in + mark
constexpr int DI = 512;            // d_inner
constexpr int DS = 16;             // d_state
constexpr int PL = 96, CO = 64;    // pred_len, c_out
constexpr int NC = 16, CLEN = 128; // scan chunks
constexpr int TSTART = L - PL;     // 1952
constexpr int C0 = TSTART / CLEN;  // 15 (chunk containing TSTART)
constexpr int T0 = C0 * CLEN;      // 1920

// ---- workspace layout (float offsets) ----
constexpr size_t o_dt   = 0;                          // B*L*DI (dt after k_xdb)
constexpr size_t o_xc   = o_dt  + (size_t)B*L*DI;     // B*L*DI
constexpr size_t o_z    = o_xc  + (size_t)B*L*DI;     // B*PL*DI  (holds silu(z))
constexpr size_t o_Bm   = o_z   + (size_t)B*PL*DI;    // B*L*DS
constexpr size_t o_Cm   = o_Bm  + (size_t)B*L*DS;     // B*L*DS
constexpr size_t o_WfT  = o_Cm  + (size_t)B*L*DS;     // 69*1024 (row 68 = fused bias)
constexpr size_t o_WxT  = o_WfT + 69*1024;            // 512*48 (unused now, kept for layout)
constexpr size_t o_WdtT = o_WxT + 512*48;             // 16*512
constexpr size_t o_Wcb  = o_WdtT+ 16*512;             // 512*64
constexpr size_t o_P    = o_Wcb + 512*64;             // NC*B*DI*DS
constexpr size_t o_Bc   = o_P   + (size_t)NC*B*DI*DS; // NC*B*DI*DS
constexpr size_t o_yf   = o_Bc  + (size_t)NC*B*DI*DS; // B*PL*DI

// ---------- K0: weight fusion / transposes ----------
__global__ __launch_bounds__(256) void k_prep(
        const float* __restrict__ W_it, const float* __restrict__ b_it,
        const float* __restrict__ W_in, const float* __restrict__ W_out,
        const float* __restrict__ W_fc, const float* __restrict__ W_x,
        const float* __restrict__ W_dt, float* __restrict__ ws)
{
    int idx = blockIdx.x * 256 + threadIdx.x;
    float* WfT  = ws + o_WfT;
    float* WdtT = ws + o_WdtT;
    float* Wcb  = ws + o_Wcb;
    if (idx < 69*1024) {
        int k = idx / 1024, j = idx % 1024;
        float acc = 0.f;
        if (k < 68) { for (int m = 0; m < 256; ++m) acc += W_in[j*256+m] * W_it[m*68+k]; }
        else        { for (int m = 0; m < 256; ++m) acc += W_in[j*256+m] * b_it[m]; }
        WfT[idx] = acc;
        return;
    }
    idx -= 69*1024;
    if (idx < 512*48) return;   // transposed WxT no longer needed
    idx -= 512*48;
    if (idx < 16*512) { int r = idx>>9, j = idx&511; WdtT[idx] = W_dt[j*16+r]; return; }
    idx -= 16*512;
    if (idx < 512*64) {
        int d = idx>>6, c = idx&63;
        float acc = 0.f;
        for (int m = 0; m < 256; ++m) acc += W_fc[c*256+m] * W_out[m*512+d];
        Wcb[idx] = acc;
    }
}

// ---------- K1: fused input-proj + causal conv(4) + SiLU -> xc; plus silu(z) ----------
__global__ __launch_bounds__(256) void k_xzc(const float* __restrict__ x_enc,
        const float* __restrict__ x_mark, const float* __restrict__ conv_w,
        const float* __restrict__ conv_b, float* __restrict__ ws)
{
    __shared__ float s68[19][IN68];
    __shared__ float xps[19][DI];
    const float* WfT = ws + o_WfT;
    int tid = threadIdx.x;
    if (blockIdx.x < 1024) {
        int bt0 = blockIdx.x * 16;
        int b = bt0 >> 11, tl0 = bt0 & (L-1);
        for (int i = tid; i < 19*IN68; i += 256) {
            int row = i / IN68, k = i % IN68;
            int t = tl0 - 3 + row;
            float v = 0.f;
            if (t >= 0) v = (k < 64) ? x_enc[(b*L + t)*64 + k] : x_mark[(b*L + t)*4 + (k-64)];
            s68[row][k] = v;
        }
        __syncthreads();
        float a0[19], a1[19];
        #pragma unroll
        for (int r = 0; r < 19; ++r) { a0[r] = 0.f; a1[r] = 0.f; }
        for (int k = 0; k < IN68; ++k) {
            float w0 = WfT[k*1024 + tid];
            float w1 = WfT[k*1024 + 256 + tid];
            #pragma unroll
            for (int r = 0; r < 19; ++r) {
                float v = s68[r][k];
                a0[r] += v*w0; a1[r] += v*w1;
            }
        }
        float b0 = WfT[68*1024 + tid], b1 = WfT[68*1024 + 256 + tid];
        #pragma unroll
        for (int r = 0; r < 19; ++r) {
            bool valid = (tl0 - 3 + r) >= 0;
            xps[r][tid]       = valid ? a0[r] + b0 : 0.f;
            xps[r][tid + 256] = valid ? a1[r] + b1 : 0.f;
        }
        __syncthreads();
        float cw0[4], cw1[4];
        #pragma unroll
        for (int i = 0; i < 4; ++i) { cw0[i] = conv_w[tid*4+i]; cw1[i] = conv_w[(tid+256)*4+i]; }
        float cb0 = conv_b[tid], cb1 = conv_b[tid+256];
        float* xc = ws + o_xc;
        #pragma unroll
        for (int tt = 0; tt < 16; ++tt) {
            float acc0 = cb0, acc1 = cb1;
            #pragma unroll
            for (int i = 0; i < 4; ++i) {
                acc0 += xps[tt+i][tid]     * cw0[i];
                acc1 += xps[tt+i][tid+256] * cw1[i];
            }
            float v0 = acc0 / (1.f + __expf(-acc0));
            float v1 = acc1 / (1.f + __expf(-acc1));
            size_t bt = bt0 + tt;
            xc[bt*DI + tid]       = v0;
            xc[bt*DI + 256 + tid] = v1;
        }
    } else {
        // silu(z) for rows t in [TSTART, L)
        int zb = blockIdx.x - 1024;        // 0..47
        int b = zb / 6;
        int tl0 = TSTART + (zb % 6) * 16;
        for (int i = tid; i < 16*IN68; i += 256) {
            int row = i / IN68, k = i % IN68;
            int t = tl0 + row;
            s68[row][k] = (k < 64) ? x_enc[(b*L + t)*64 + k] : x_mark[(b*L + t)*4 + (k-64)];
        }
        __syncthreads();
        float a2[16], a3[16];
        #pragma unroll
        for (int r = 0; r < 16; ++r) { a2[r] = 0.f; a3[r] = 0.f; }
        for (int k = 0; k < IN68; ++k) {
            float w2 = WfT[k*1024 + 512 + tid];
            float w3 = WfT[k*1024 + 768 + tid];
            #pragma unroll
            for (int r = 0; r < 16; ++r) {
                float v = s68[r][k];
                a2[r] += v*w2; a3[r] += v*w3;
            }
        }
        float b2 = WfT[68*1024 + 512 + tid], b3 = WfT[68*1024 + 768 + tid];
        float* z = ws + o_z;
        #pragma unroll
        for (int r = 0; r < 16; ++r) {
            float z0 = a2[r] + b2, z1 = a3[r] + b3;
            size_t row = b*PL + (tl0 + r - TSTART);
            z[row*DI + tid]       = z0 / (1.f + __expf(-z0));
            z[row*DI + 256 + tid] = z1 / (1.f + __expf(-z1));
        }
    }
}

// ---------- K2: register-tiled x_db GEMM + dt = softplus ----------
// Block: 32 t-rows. GEMM1: s[32][48] = xc_tile @ W_x^T, K-tiled by 128,
// xc & W_x tiles staged in LDS (padded float4), thread = 2t x 3r register tile.
// GEMM2: dt[32][512] with W_dt columns held in registers, s via LDS broadcast.
#define DOT4(a, xv, wv) { a = fmaf((xv).x, (wv).x, a); a = fmaf((xv).y, (wv).y, a); \
                          a = fmaf((xv).z, (wv).z, a); a = fmaf((xv).w, (wv).w, a); }
__global__ __launch_bounds__(256) void k_xdb(const float* __restrict__ W_x,
        const float* __restrict__ b_dt, float* __restrict__ ws)
{
    __shared__ float4 xc4[32][33];   // 16.9 KB (pad 33 to break bank aliasing)
    __shared__ float4 W4[48][33];    // 25.3 KB
    __shared__ float  s_s[32][48];   // 6 KB
    const float4* xcg = (const float4*)(ws + o_xc);
    const float4* Wxg = (const float4*)W_x;
    const float*  WdtT= ws + o_WdtT;
    float* dt = ws + o_dt;
    float* Bm = ws + o_Bm;
    float* Cm = ws + o_Cm;
    int tid = threadIdx.x;
    int bt0 = blockIdx.x * 32;
    int rg = tid & 15, tg = tid >> 4;
    int r0 = rg*3, t0 = tg*2;
    float acc[2][3] = {{0.f,0.f,0.f},{0.f,0.f,0.f}};
    for (int kt = 0; kt < 4; ++kt) {
        for (int v = tid; v < 32*32; v += 256) {
            int row = v >> 5, c4 = v & 31;
            xc4[row][c4] = xcg[(size_t)(bt0+row)*128 + kt*32 + c4];
        }
        for (int v = tid; v < 48*32; v += 256) {
            int row = v >> 5, c4 = v & 31;
            W4[row][c4] = Wxg[(size_t)row*128 + kt*32 + c4];
        }
        __syncthreads();
        #pragma unroll 8
        for (int k4 = 0; k4 < 32; ++k4) {
            float4 x0 = xc4[t0][k4],   x1 = xc4[t0+1][k4];
            float4 w0 = W4[r0][k4],    w1 = W4[r0+1][k4], w2 = W4[r0+2][k4];
            DOT4(acc[0][0], x0, w0); DOT4(acc[0][1], x0, w1); DOT4(acc[0][2], x0, w2);
            DOT4(acc[1][0], x1, w0); DOT4(acc[1][1], x1, w1); DOT4(acc[1][2], x1, w2);
        }
        __syncthreads();
    }
    #pragma unroll
    for (int j = 0; j < 3; ++j) {
        s_s[t0][r0+j]   = acc[0][j];
        s_s[t0+1][r0+j] = acc[1][j];
    }
    __syncthreads();
    // Bm / Cm from s columns 16..47 (coalesced global writes)
    for (int i = tid; i < 32*16; i += 256) {
        int t = i >> 4, n = i & 15;
        Bm[(size_t)(bt0+t)*DS + n] = s_s[t][16+n];
        Cm[(size_t)(bt0+t)*DS + n] = s_s[t][32+n];
    }
    // GEMM2: thread owns columns j0=tid, j1=tid+256; W_dt cols in registers
    float wd0[16], wd1[16];
    int j0 = tid, j1 = tid + 256;
    #pragma unroll
    for (int n = 0; n < 16; ++n) { wd0[n] = WdtT[n*512 + j0]; wd1[n] = WdtT[n*512 + j1]; }
    float bb0 = b_dt[j0], bb1 = b_dt[j1];
    for (int t = 0; t < 32; ++t) {
        float a0 = bb0, a1 = bb1;
        #pragma unroll
        for (int n = 0; n < 16; ++n) {
            float sv = s_s[t][n];     // LDS broadcast
            a0 = fmaf(sv, wd0[n], a0);
            a1 = fmaf(sv, wd1[n], a1);
        }
        float sp0 = fmaxf(a0, 0.f) + log1pf(expf(-fabsf(a0)));
        float sp1 = fmaxf(a1, 0.f) + log1pf(expf(-fabsf(a1)));
        dt[(size_t)(bt0+t)*DI + j0] = sp0;
        dt[(size_t)(bt0+t)*DI + j1] = sp1;
    }
}

// ---------- K3: chunked scan phase 1 (chunks 0..14): per-chunk (prod a, local h) ----------
__global__ __launch_bounds__(256) void k_scan1(const float* __restrict__ A_log,
        float* __restrict__ ws)
{
    __shared__ float bs[CLEN*DS];   // 8 KB
    const float* dt = ws + o_dt;
    const float* xc = ws + o_xc;
    const float* Bm = ws + o_Bm;
    float* P  = ws + o_P;
    float* Bc = ws + o_Bc;
    int tid = threadIdx.x;
    int bx = blockIdx.x;            // 240 = B * 15 * 2
    int b = bx / 30;
    int r = bx % 30;
    int c = r % 15;
    int half = r / 15;
    int d = half*256 + tid;
    float aco[16], h[16];
    #pragma unroll
    for (int n = 0; n < 16; ++n) {
        aco[n] = -__expf(A_log[d*DS + n]);
        h[n] = 0.f;
    }
    size_t btBase = (size_t)b*L + c*CLEN;
    for (int i = tid; i < CLEN*DS; i += 256) bs[i] = Bm[btBase*DS + i];
    __syncthreads();
    const float* dtp = dt + btBase*DI + d;
    const float* xcp = xc + btBase*DI + d;
    float sdt = 0.f;
    float dtv = dtp[0], xcv = xcp[0];
    for (int t = 0; t < CLEN; ++t) {
        float dtn = 0.f, xcn = 0.f;
        if (t < CLEN-1) { dtn = dtp[(size_t)(t+1)*DI]; xcn = xcp[(size_t)(t+1)*DI]; }
        float dtx = dtv * xcv;
        sdt += dtv;
        #pragma unroll
        for (int n = 0; n < 16; ++n) {
            float a = __expf(aco[n] * dtv);
            h[n] = fmaf(a, h[n], bs[t*DS + n] * dtx);
        }
        dtv = dtn; xcv = xcn;
    }
    size_t base = (((size_t)c*B + b)*DI + d)*DS;
    #pragma unroll
    for (int n = 0; n < 16; ++n) {
        P [base + n] = __expf(aco[n] * sdt);
        Bc[base + n] = h[n];
    }
}

// ---------- K4: combine chunks 0..14 + replay last chunk from LDS + gate ----------
__global__ __launch_bounds__(512) void k_scan2(const float* __restrict__ A_log,
        const float* __restrict__ Dp, float* __restrict__ ws)
{
    __shared__ float dts[CLEN*32];  // 16 KB
    __shared__ float xds[CLEN*32];  // 16 KB
    __shared__ float bss[CLEN*DS];  // 8 KB
    __shared__ float css[CLEN*DS];  // 8 KB
    __shared__ float szs[PL*32];    // 12 KB
    const float* dt = ws + o_dt;
    const float* xc = ws + o_xc;
    const float* Bm = ws + o_Bm;
    const float* Cm = ws + o_Cm;
    const float* z  = ws + o_z;
    const float* P  = ws + o_P;
    const float* Bc = ws + o_Bc;
    float* yf = ws + o_yf;
    int tid = threadIdx.x;
    int bx = blockIdx.x;           // 128 = B * 16
    int b = bx >> 4, dtile = bx & 15;
    int n = tid & 15, dl = tid >> 4;   // dl in [0,32)
    int d = dtile*32 + dl;
    size_t btBase = (size_t)b*L + T0;
    for (int i = tid; i < CLEN*32; i += 512) {
        int tt = i >> 5, j = i & 31;
        size_t g = (btBase + tt)*DI + dtile*32 + j;
        dts[i] = dt[g];
        xds[i] = xc[g];
    }
    for (int i = tid; i < CLEN*DS; i += 512) {
        bss[i] = Bm[btBase*DS + i];
        css[i] = Cm[btBase*DS + i];
    }
    for (int i = tid; i < PL*32; i += 512) {
        int tt = i >> 5, j = i & 31;
        szs[i] = z[((size_t)b*PL + tt)*DI + dtile*32 + j];
    }
    float aco = -__expf(A_log[d*DS + n]);
    float Dv = Dp[d];
    float h = 0.f;
    for (int c = 0; c < C0; ++c) {
        size_t idx = (((size_t)c*B + b)*DI + d)*DS + n;
        h = P[idx]*h + Bc[idx];
    }
    __syncthreads();
    for (int t = 0; t < CLEN; ++t) {
        float dtv = dts[t*32 + dl];
        float xcv = xds[t*32 + dl];
        float bv  = bss[t*DS + n];
        float a = __expf(aco * dtv);
        h = fmaf(a, h, dtv * bv * xcv);
        if (t >= TSTART - T0) {
            float y = h * css[t*DS + n];
            y += __shfl_xor(y, 1, 16);
            y += __shfl_xor(y, 2, 16);
            y += __shfl_xor(y, 4, 16);
            y += __shfl_xor(y, 8, 16);
            if (n == 0) {
                int row = t - (TSTART - T0);
                yf[((size_t)b*PL + row)*DI + d] = (y + xcv*Dv) * szs[row*32 + dl];
            }
        }
    }
}

// ---------- K5: out = yf @ W_comb.T + b_fc ----------
__global__ __launch_bounds__(64) void k_final(const float* __restrict__ b_fc,
        float* __restrict__ out, const float* __restrict__ ws_c)
{
    __shared__ float ys[DI];
    const float* yf  = ws_c + o_yf;
    const float* Wcb = ws_c + o_Wcb;
    int row = blockIdx.x;     // B*PL = 768
    int c = threadIdx.x;      // 64
    for (int i = c; i < DI; i += 64) ys[i] = yf[(size_t)row*DI + i];
    __syncthreads();
    float a0 = b_fc[c], a1 = 0.f, a2 = 0.f, a3 = 0.f;
    for (int d = 0; d < DI; d += 4) {
        a0 += ys[d]   * Wcb[d*64 + c];
        a1 += ys[d+1] * Wcb[(d+1)*64 + c];
        a2 += ys[d+2] * Wcb[(d+2)*64 + c];
        a3 += ys[d+3] * Wcb[(d+3)*64 + c];
    }
    out[row*CO + c] = (a0+a1) + (a2+a3);
}

extern "C" void kernel_launch(void* const* d_in, const int* in_sizes, int n_in,
                              void* d_out, int out_size, void* d_ws, size_t ws_size,
                              hipStream_t stream)
{
    const float* x_enc  = (const float*)d_in[0];
    const float* x_mark = (const float*)d_in[1];
    const float* W_it   = (const float*)d_in[4];
    const float* b_it   = (const float*)d_in[5];
    const float* W_in   = (const float*)d_in[6];
    const float* conv_w = (const float*)d_in[7];
    const float* conv_b = (const float*)d_in[8];
    const float* W_x    = (const float*)d_in[9];
    const float* W_dt   = (const float*)d_in[10];
    const float* b_dt   = (const float*)d_in[11];
    const float* A_log  = (const float*)d_in[12];
    const float* Dp     = (const float*)d_in[13];
    const float* W_out  = (const float*)d_in[14];
    const float* W_fc   = (const float*)d_in[15];
    const float* b_fc   = (const float*)d_in[16];
    float* ws  = (float*)d_ws;
    float* out = (float*)d_out;

    constexpr int prep_total = 69*1024 + 512*48 + 16*512 + 512*64;
    k_prep <<<(prep_total + 255)/256, 256, 0, stream>>>(W_it, b_it, W_in, W_out, W_fc, W_x, W_dt, ws);
    k_xzc  <<<1072,     256, 0, stream>>>(x_enc, x_mark, conv_w, conv_b, ws);
    k_xdb  <<<512,      256, 0, stream>>>(W_x, b_dt, ws);
    k_scan1<<<B*15*2,   256, 0, stream>>>(A_log, ws);
    k_scan2<<<B*16,     512, 0, stream>>>(A_log, Dp, ws);
    k_final<<<B*PL,     64,  0, stream>>>(b_fc, out, ws);
}